// Round 9
// baseline (91.267 us; speedup 1.0000x reference)
//
#include <hip/hip_runtime.h>
#include <math.h>

#define BATCH   4
#define NPTS    8192
#define THREADS 256
#define CHUNK   1024                  // targets staged per LDS chunk
#define NCHUNKS (NPTS / CHUNK)        // 8
#define NBLOCKS (2 * BATCH * (NPTS / 128))   // 512: (dir, b, 128-query group)

typedef _Float16 h8   __attribute__((ext_vector_type(8)));   // 4 VGPRs
typedef float    f16v __attribute__((ext_vector_type(16)));  // 16 VGPRs

// ---------------------------------------------------------------------------
// K0 (r6-verified): transform both clouds into MFMA-ready split-f16 records.
// lo (k 0..7):  [-2thx,-2thy,-2thz, tth, -2thx,-2thy,-2thz, ttl]
// hi (k 8..15): [-2tlx,-2tly,-2tlz, 0,0,0,0,0]
// With A = [qh,1, ql,1 | qh,0..] one mfma_f32_32x32x16_f16 gives tt - 2 q~.t~
// (omitted ql.tl ~ 1e-6 relative — r6/r8 measured absmax 0.0).
// ---------------------------------------------------------------------------
__global__ __launch_bounds__(THREADS)
void chamfer_transform(const float* __restrict__ pred,
                       const float* __restrict__ target,
                       h8* __restrict__ trans_lo,
                       h8* __restrict__ trans_hi)
{
    const int p   = blockIdx.x * THREADS + threadIdx.x;   // 0..65535
    const int arr = p >> 15;                               // 0=pred, 1=target
    const int pb  = p & 32767;

    const float* src = (arr ? target : pred) + (size_t)pb * 3;
    const float x = src[0], y = src[1], z = src[2];

    const _Float16 hx = (_Float16)x;  const _Float16 lx = (_Float16)(x - (float)hx);
    const _Float16 hy = (_Float16)y;  const _Float16 ly = (_Float16)(y - (float)hy);
    const _Float16 hz = (_Float16)z;  const _Float16 lz = (_Float16)(z - (float)hz);

    const float tx = (float)hx + (float)lx;
    const float ty = (float)hy + (float)ly;
    const float tz = (float)hz + (float)lz;
    const float tt = fmaf(tx, tx, fmaf(ty, ty, tz * tz));
    const _Float16 tth = (_Float16)tt;
    const _Float16 ttl = (_Float16)(tt - (float)tth);

    const _Float16 n2 = (_Float16)(-2.0f);
    const _Float16 zz = (_Float16)0.0f;
    h8 lo = { n2 * hx, n2 * hy, n2 * hz, tth,
              n2 * hx, n2 * hy, n2 * hz, ttl };
    h8 hi = { n2 * lx, n2 * ly, n2 * lz, zz, zz, zz, zz, zz };

    trans_lo[p] = lo;
    trans_hi[p] = hi;
}

// ---------------------------------------------------------------------------
// K1: per-wave 32-query tile vs all 8192 targets. Latency-oriented inner loop:
// 4 B-frags register-prefetched (one lgkm wait / 4 tiles), 4 MFMAs in flight,
// 5-deep fminf chain per reg (compiler fuses to v_min3 pairs with proper
// MFMA-hazard handling — r7 showed hand-asm min3 on MFMA dests races).
// Staging is pure uint4 copies (transform precomputed in K0).
// Epilogue (r8-verified): butterfly min over 32 cols, +|q|^2, sqrt, block sum.
// ---------------------------------------------------------------------------
__global__ __launch_bounds__(THREADS)
void chamfer_min_kernel(const float* __restrict__ pred,
                        const float* __restrict__ target,
                        const uint4* __restrict__ trans_lo,
                        const uint4* __restrict__ trans_hi,
                        float* __restrict__ bsum)
{
    __shared__ uint4 slo[CHUNK];   // 16 KB
    __shared__ uint4 shi[CHUNK];   // 16 KB
    __shared__ float sqq[128];
    __shared__ float wsum[8];

    const int tid  = threadIdx.x;
    const int lane = tid & 63;
    const int wave = tid >> 6;
    const int n    = lane & 31;
    const int hi   = lane >> 5;

    const int bid = blockIdx.x;
    const int qg  = bid & 63;
    const int b   = (bid >> 6) & 3;
    const int dir = bid >> 8;        // 0: q=pred, db=target ; 1: swapped

    const float* qraw = ((dir == 0) ? pred : target) + (size_t)b * NPTS * 3;
    const int    darr = (dir == 0) ? 1 : 0;          // db half of trans arrays
    const int    qtbase = qg * 128 + wave * 32;

    // ---- A fragment (split-f16 query) + |q|^2 stash ----
    h8 afrag;
    {
        const float* qp = qraw + (size_t)(qtbase + n) * 3;
        const float x = qp[0], y = qp[1], z = qp[2];
        const _Float16 hx = (_Float16)x; const _Float16 lx = (_Float16)(x - (float)hx);
        const _Float16 hy = (_Float16)y; const _Float16 ly = (_Float16)(y - (float)hy);
        const _Float16 hz = (_Float16)z; const _Float16 lz = (_Float16)(z - (float)hz);
        const _Float16 one  = (_Float16)1.0f;
        const _Float16 zero = (_Float16)0.0f;
        if (hi == 0) {
            afrag = (h8){hx, hy, hz, one, lx, ly, lz, one};
            sqq[wave * 32 + n] = fmaf(x, x, fmaf(y, y, z * z));
        } else {
            afrag = (h8){hx, hy, hz, zero, zero, zero, zero, zero};
        }
    }

    float mn[16];
    #pragma unroll
    for (int i = 0; i < 16; ++i) mn[i] = 3.0e38f;

    const f16v zc = {};                              // hoisted zero accum
    const uint4* bsrc = hi ? shi : slo;
    const size_t gbase = (size_t)(darr * 4 + b) * NPTS;

    #pragma unroll 1
    for (int c = 0; c < NCHUNKS; ++c) {
        // ---- stage chunk: pure coalesced copies ----
        const size_t cb = gbase + (size_t)c * CHUNK;
        #pragma unroll
        for (int r = 0; r < 4; ++r) {
            slo[r * THREADS + tid] = trans_lo[cb + r * THREADS + tid];
            shi[r * THREADS + tid] = trans_hi[cb + r * THREADS + tid];
        }
        __syncthreads();

        // ---- 32 tiles, 4-deep prefetch, 4 MFMAs in flight ----
        h8 bf0 = *(const h8*)&bsrc[0 * 32 + n];
        h8 bf1 = *(const h8*)&bsrc[1 * 32 + n];
        h8 bf2 = *(const h8*)&bsrc[2 * 32 + n];
        h8 bf3 = *(const h8*)&bsrc[3 * 32 + n];

        #pragma unroll 1
        for (int t = 0; t < 32; t += 4) {
            const f16v d0 = __builtin_amdgcn_mfma_f32_32x32x16_f16(afrag, bf0, zc, 0, 0, 0);
            const f16v d1 = __builtin_amdgcn_mfma_f32_32x32x16_f16(afrag, bf1, zc, 0, 0, 0);
            const f16v d2 = __builtin_amdgcn_mfma_f32_32x32x16_f16(afrag, bf2, zc, 0, 0, 0);
            const f16v d3 = __builtin_amdgcn_mfma_f32_32x32x16_f16(afrag, bf3, zc, 0, 0, 0);

            const int tn = (t + 4) & 31;             // wraps on last iter (reads unused)
            bf0 = *(const h8*)&bsrc[(tn + 0) * 32 + n];
            bf1 = *(const h8*)&bsrc[(tn + 1) * 32 + n];
            bf2 = *(const h8*)&bsrc[(tn + 2) * 32 + n];
            bf3 = *(const h8*)&bsrc[(tn + 3) * 32 + n];

            #pragma unroll
            for (int i = 0; i < 16; ++i)
                mn[i] = fminf(fminf(fminf(fminf(mn[i], d0[i]), d1[i]), d2[i]), d3[i]);
        }
        __syncthreads();
    }

    // ---- butterfly min over the 32 columns (within each 32-half) ----
    #pragma unroll
    for (int mask = 1; mask <= 16; mask <<= 1) {
        #pragma unroll
        for (int i = 0; i < 16; ++i)
            mn[i] = fminf(mn[i], __shfl_xor(mn[i], mask, 64));
    }

    // ---- epilogue (r8-verified): qq + clamp + sqrt + block sum ----
    if (n == 0) {
        float s = 0.0f;
        #pragma unroll
        for (int i = 0; i < 16; ++i) {
            const int row = (i & 3) + 8 * (i >> 2) + 4 * hi;
            s += sqrtf(fmaxf(sqq[wave * 32 + row] + mn[i], 1e-12f));
        }
        wsum[wave * 2 + hi] = s;
    }
    __syncthreads();
    if (tid == 0) {
        float t = 0.0f;
        #pragma unroll
        for (int k = 0; k < 8; ++k) t += wsum[k];
        bsum[bid] = t;
    }
}

// final: sum 512 block sums, write mean over batches
__global__ __launch_bounds__(THREADS)
void chamfer_final(const float* __restrict__ bsum,
                   float* __restrict__ out)
{
    const int tid = threadIdx.x;
    float v = bsum[tid] + bsum[tid + 256];
    #pragma unroll
    for (int off = 32; off > 0; off >>= 1)
        v += __shfl_down(v, off, 64);

    __shared__ float wsum[4];
    if ((tid & 63) == 0) wsum[tid >> 6] = v;
    __syncthreads();
    if (tid == 0) out[0] = (wsum[0] + wsum[1] + wsum[2] + wsum[3]) * (1.0f / BATCH);
}

extern "C" void kernel_launch(void* const* d_in, const int* in_sizes, int n_in,
                              void* d_out, int out_size, void* d_ws, size_t ws_size,
                              hipStream_t stream)
{
    const float* pred   = (const float*)d_in[0];
    const float* target = (const float*)d_in[1];
    float* out          = (float*)d_out;

    h8*    trans_lo = (h8*)d_ws;                                // 1 MB
    h8*    trans_hi = (h8*)((char*)d_ws + (size_t)65536 * 16);  // 1 MB
    float* bsum     = (float*)((char*)d_ws + (size_t)131072 * 16);

    chamfer_transform<<<256, THREADS, 0, stream>>>(pred, target, trans_lo, trans_hi);
    chamfer_min_kernel<<<NBLOCKS, THREADS, 0, stream>>>(
        pred, target, (const uint4*)trans_lo, (const uint4*)trans_hi, bsum);
    chamfer_final<<<1, THREADS, 0, stream>>>(bsum, out);
}